// Round 4
// baseline (489.068 us; speedup 1.0000x reference)
//
#include <hip/hip_runtime.h>
#include <hip/hip_bf16.h>
#include <stdint.h>

#define T_TOK 4096
#define D_DIM 1024
#define E_EXP 8
#define I_DIM 938
#define TWO_I 1876
#define NP2 2048       // padded 2I: gate rows [0,1024), up rows [1024,2048)
#define IP 1024        // padded I (h cols, down K)

typedef __attribute__((ext_vector_type(8))) short bf16x8;
typedef __attribute__((ext_vector_type(4))) float f32x4;
typedef __attribute__((ext_vector_type(8))) unsigned short u16x8;
typedef __attribute__((ext_vector_type(4))) unsigned short u16x4;

static __device__ __forceinline__ unsigned short f2bf(float f) {
  union { float f; uint32_t u; } v; v.f = f;
  uint32_t r = v.u + 0x7fffu + ((v.u >> 16) & 1u);
  return (unsigned short)(r >> 16);
}
static __device__ __forceinline__ void gload16(const void* g, void* l) {
  __builtin_amdgcn_global_load_lds((__attribute__((address_space(1))) void*)g,
                                   (__attribute__((address_space(3))) void*)l, 16, 0, 0);
}

// ---------------- x fp32 -> bf16 ----------------
__global__ __launch_bounds__(256) void cvt_x_kernel(const float* __restrict__ x,
                                                    unsigned short* __restrict__ xb) {
  int i = blockIdx.x * 256 + threadIdx.x;
  float4 v = reinterpret_cast<const float4*>(x)[i];
  u16x4 o;
  o[0] = f2bf(v.x); o[1] = f2bf(v.y); o[2] = f2bf(v.z); o[3] = f2bf(v.w);
  reinterpret_cast<u16x4*>(xb)[i] = o;
}

// ---------------- router: top-2 (idx, weight) per token ----------------
__global__ __launch_bounds__(256) void router_kernel(const float* __restrict__ x,
                                                     const float* __restrict__ gw,
                                                     int* __restrict__ ti,
                                                     float* __restrict__ tw) {
  int t = blockIdx.x * 4 + (threadIdx.x >> 6);
  int lane = threadIdx.x & 63;
  const float* xp = x + (size_t)t * D_DIM;
  float xv[16];
  #pragma unroll
  for (int i = 0; i < 16; ++i) xv[i] = xp[lane + i * 64];
  float logit[E_EXP];
  #pragma unroll
  for (int e = 0; e < E_EXP; ++e) {
    const float* wp = gw + (size_t)e * D_DIM;
    float s = 0.f;
    #pragma unroll
    for (int i = 0; i < 16; ++i) s += xv[i] * wp[lane + i * 64];
    #pragma unroll
    for (int o = 32; o; o >>= 1) s += __shfl_xor(s, o);
    logit[e] = s;
  }
  float mx = logit[0];
  #pragma unroll
  for (int e = 1; e < E_EXP; ++e) mx = fmaxf(mx, logit[e]);
  float p[E_EXP], sum = 0.f;
  #pragma unroll
  for (int e = 0; e < E_EXP; ++e) { p[e] = __expf(logit[e] - mx); sum += p[e]; }
  int i1 = 0; float p1 = p[0];
  #pragma unroll
  for (int e = 1; e < E_EXP; ++e) if (p[e] > p1) { p1 = p[e]; i1 = e; }
  int i2 = -1; float p2 = -1.f;
  #pragma unroll
  for (int e = 0; e < E_EXP; ++e) if (e != i1 && p[e] > p2) { p2 = p[e]; i2 = e; }
  float P1 = p1 / sum, P2 = p2 / sum;
  float denom = P1 + P2 + 1e-8f;
  if (lane == 0) {
    ti[2 * t] = i1; ti[2 * t + 1] = i2;
    tw[2 * t] = P1 / denom; tw[2 * t + 1] = P2 / denom;
  }
}

__global__ void zero_cnt_kernel(int* cnt) { if (threadIdx.x < E_EXP) cnt[threadIdx.x] = 0; }

__global__ __launch_bounds__(256) void assign_kernel(const int* __restrict__ ti,
                                                     const float* __restrict__ tw,
                                                     int* __restrict__ cnt,
                                                     int* __restrict__ list,
                                                     float* __restrict__ wl, int cap) {
  int t = blockIdx.x * 256 + threadIdx.x;
  #pragma unroll
  for (int j = 0; j < 2; ++j) {
    int e = ti[2 * t + j];
    float w = tw[2 * t + j];
    int slot = atomicAdd(&cnt[e], 1);
    if (slot < cap) { list[e * cap + slot] = t; wl[e * cap + slot] = w; }
  }
}

// ---- transpose gate_up: w[k][col] -> wT[n][k] bf16; n<1024 gate, else up ----
__global__ __launch_bounds__(256) void transpose_gu_kernel(
    const float* __restrict__ sgu, const float* __restrict__ egu,
    unsigned short* __restrict__ wT) {
  int e = blockIdx.z;
  const float* w = (e == 0) ? sgu : egu + (size_t)(e - 1) * D_DIM * TWO_I;
  unsigned short* o = wT + (size_t)e * NP2 * D_DIM;
  int k0 = blockIdx.x * 64, n0 = blockIdx.y * 32;
  __shared__ unsigned short lds[32][72];
  int tid = threadIdx.x;
  int nn = tid & 31, kr = tid >> 5;
  int n = n0 + nn;
  int src = (n < IP) ? ((n < I_DIM) ? n : -1)
                     : ((n - IP < I_DIM) ? I_DIM + (n - IP) : -1);
  #pragma unroll
  for (int i = 0; i < 8; ++i) {
    int k = k0 + kr + i * 8;
    float f = (src >= 0) ? w[(size_t)k * TWO_I + src] : 0.f;
    lds[nn][kr + i * 8] = f2bf(f);
  }
  __syncthreads();
  int nr = tid >> 3, kc = (tid & 7) * 8;
  u16x8 v;
  #pragma unroll
  for (int j = 0; j < 8; ++j) v[j] = lds[nr][kc + j];
  *reinterpret_cast<u16x8*>(&o[(size_t)(n0 + nr) * D_DIM + k0 + kc]) = v;
}

// ---- transpose down: wd[k][n] -> wT[n][k] bf16, k padded to 1024 ----
__global__ __launch_bounds__(256) void transpose_d_kernel(
    const float* __restrict__ sdn, const float* __restrict__ edn,
    unsigned short* __restrict__ wT) {
  int e = blockIdx.z;
  const float* w = (e == 0) ? sdn : edn + (size_t)(e - 1) * I_DIM * D_DIM;
  unsigned short* o = wT + (size_t)e * D_DIM * IP;
  int k0 = blockIdx.x * 64, n0 = blockIdx.y * 32;
  __shared__ unsigned short lds[32][72];
  int tid = threadIdx.x;
  int nn = tid & 31, kr = tid >> 5;
  #pragma unroll
  for (int i = 0; i < 8; ++i) {
    int k = k0 + kr + i * 8;
    float f = (k < I_DIM) ? w[(size_t)k * D_DIM + n0 + nn] : 0.f;
    lds[nn][kr + i * 8] = f2bf(f);
  }
  __syncthreads();
  int nr = tid >> 3, kc = (tid & 7) * 8;
  u16x8 v;
  #pragma unroll
  for (int j = 0; j < 8; ++j) v[j] = lds[nr][kc + j];
  *reinterpret_cast<u16x8*>(&o[(size_t)(n0 + nr) * IP + k0 + kc]) = v;
}

// ------- fused GEMM1+SwiGLU, shared+routed in one launch, 2-phase dbuf -------
// 1D grid 2304, XCD-swizzled. wg -> e (0=shared,1..8 routed), mb (<32), nb (<8)
__global__ __launch_bounds__(256) void gemm1_kernel(
    const unsigned short* __restrict__ xb,
    const unsigned short* __restrict__ wTgu,
    unsigned short* __restrict__ h_sh,
    unsigned short* __restrict__ h_g,
    const int* __restrict__ list, const int* __restrict__ cnt, int cap) {
  const int orig = blockIdx.x;
  const int wg = (orig & 7) * (gridDim.x >> 3) + (orig >> 3);   // bijective, nwg%8==0
  const int e = wg >> 8;
  const int rem = wg & 255;
  const int m0 = (rem >> 3) * 128, n0 = (rem & 7) * 128;
  int count = T_TOK;
  const unsigned short* w = wTgu;
  unsigned short* h = h_sh;
  if (e > 0) {
    count = min(cnt[e - 1], cap);
    if (m0 >= count) return;
    w = wTgu + (size_t)e * NP2 * D_DIM;
    h = h_g + (size_t)(e - 1) * cap * IP;
  }

  __shared__ __align__(16) unsigned short a_lds[2][128 * 32];
  __shared__ __align__(16) unsigned short b_lds[2][256 * 32];
  const int tid = threadIdx.x;
  const int wave = tid >> 6, lane = tid & 63;
  const int mw = (wave >> 1) * 64, nw = (wave & 1) * 64;
  const int fr = lane & 15, fq = lane >> 4;
  const int ko = (tid & 3) * 8;
  const int ldr = tid >> 2;

  size_t arow[2];
  #pragma unroll
  for (int r = 0; r < 2; ++r) {
    int trow = m0 + ldr + 64 * r;
    if (e > 0) trow = list[(e - 1) * cap + min(trow, count - 1)];
    arow[r] = (size_t)trow * D_DIM;
  }
  size_t brow[4];
  #pragma unroll
  for (int r = 0; r < 4; ++r) {
    int lr = ldr + 64 * r;
    int grow = (lr < 128) ? (n0 + lr) : (IP + n0 + lr - 128);
    brow[r] = (size_t)grow * D_DIM;
  }

  f32x4 accg[4][4], accu[4][4];
  #pragma unroll
  for (int m = 0; m < 4; ++m)
    #pragma unroll
    for (int n = 0; n < 4; ++n) { accg[m][n] = (f32x4)0.f; accu[m][n] = (f32x4)0.f; }

  auto stage = [&](int buf, int k0) {
    #pragma unroll
    for (int r = 0; r < 2; ++r)
      gload16(xb + arow[r] + k0 + ko, &a_lds[buf][(ldr + 64 * r) * 32 + ko]);
    #pragma unroll
    for (int r = 0; r < 4; ++r)
      gload16(w + brow[r] + k0 + ko, &b_lds[buf][(ldr + 64 * r) * 32 + ko]);
  };

  stage(0, 0);
  __syncthreads();
  int cur = 0;
  for (int t = 0; t < D_DIM / 32; ++t) {
    if (t + 1 < D_DIM / 32) stage(cur ^ 1, (t + 1) * 32);
    bf16x8 av[4], bg[4], bu[4];
    #pragma unroll
    for (int m = 0; m < 4; ++m)
      av[m] = *reinterpret_cast<const bf16x8*>(&a_lds[cur][(mw + m * 16 + fr) * 32 + fq * 8]);
    #pragma unroll
    for (int n = 0; n < 4; ++n) {
      bg[n] = *reinterpret_cast<const bf16x8*>(&b_lds[cur][(nw + n * 16 + fr) * 32 + fq * 8]);
      bu[n] = *reinterpret_cast<const bf16x8*>(&b_lds[cur][(128 + nw + n * 16 + fr) * 32 + fq * 8]);
    }
    #pragma unroll
    for (int m = 0; m < 4; ++m)
      #pragma unroll
      for (int n = 0; n < 4; ++n) {
        accg[m][n] = __builtin_amdgcn_mfma_f32_16x16x32_bf16(av[m], bg[n], accg[m][n], 0, 0, 0);
        accu[m][n] = __builtin_amdgcn_mfma_f32_16x16x32_bf16(av[m], bu[n], accu[m][n], 0, 0, 0);
      }
    __syncthreads();
    cur ^= 1;
  }
  #pragma unroll
  for (int m = 0; m < 4; ++m)
    #pragma unroll
    for (int q = 0; q < 4; ++q) {
      int t = m0 + mw + m * 16 + fq * 4 + q;
      #pragma unroll
      for (int n = 0; n < 4; ++n) {
        float g = accg[m][n][q], u = accu[m][n][q];
        float hv = (g / (1.f + __expf(-g))) * u;
        h[(size_t)t * IP + n0 + nw + n * 16 + fr] = f2bf(hv);
      }
    }
}

// ------- GEMM2 shared: out = h_sh @ Wd (plain store), 2-phase dbuf -------
__global__ __launch_bounds__(256) void gemm2_sh_kernel(
    const unsigned short* __restrict__ A,    // h_sh [T, IP]
    const unsigned short* __restrict__ B,    // wTd[0] [D, IP]
    float* __restrict__ out) {
  const int m0 = blockIdx.x * 128, n0 = blockIdx.y * 128;
  __shared__ __align__(16) unsigned short a_lds[2][128 * 32];
  __shared__ __align__(16) unsigned short b_lds[2][128 * 32];
  const int tid = threadIdx.x;
  const int wave = tid >> 6, lane = tid & 63;
  const int mw = (wave >> 1) * 64, nw = (wave & 1) * 64;
  const int fr = lane & 15, fq = lane >> 4;
  const int ko = (tid & 3) * 8;
  const int ldr = tid >> 2;

  f32x4 acc[4][4];
  #pragma unroll
  for (int m = 0; m < 4; ++m)
    #pragma unroll
    for (int n = 0; n < 4; ++n) acc[m][n] = (f32x4)0.f;

  auto stage = [&](int buf, int k0) {
    #pragma unroll
    for (int r = 0; r < 2; ++r) {
      int lr = ldr + 64 * r;
      gload16(A + (size_t)(m0 + lr) * IP + k0 + ko, &a_lds[buf][lr * 32 + ko]);
      gload16(B + (size_t)(n0 + lr) * IP + k0 + ko, &b_lds[buf][lr * 32 + ko]);
    }
  };
  stage(0, 0);
  __syncthreads();
  int cur = 0;
  for (int t = 0; t < IP / 32; ++t) {
    if (t + 1 < IP / 32) stage(cur ^ 1, (t + 1) * 32);
    bf16x8 av[4], bv[4];
    #pragma unroll
    for (int m = 0; m < 4; ++m)
      av[m] = *reinterpret_cast<const bf16x8*>(&a_lds[cur][(mw + m * 16 + fr) * 32 + fq * 8]);
    #pragma unroll
    for (int n = 0; n < 4; ++n)
      bv[n] = *reinterpret_cast<const bf16x8*>(&b_lds[cur][(nw + n * 16 + fr) * 32 + fq * 8]);
    #pragma unroll
    for (int m = 0; m < 4; ++m)
      #pragma unroll
      for (int n = 0; n < 4; ++n)
        acc[m][n] = __builtin_amdgcn_mfma_f32_16x16x32_bf16(av[m], bv[n], acc[m][n], 0, 0, 0);
    __syncthreads();
    cur ^= 1;
  }
  #pragma unroll
  for (int m = 0; m < 4; ++m)
    #pragma unroll
    for (int q = 0; q < 4; ++q) {
      int t = m0 + mw + m * 16 + fq * 4 + q;
      #pragma unroll
      for (int n = 0; n < 4; ++n)
        out[(size_t)t * D_DIM + n0 + nw + n * 16 + fr] = acc[m][n][q];
    }
}

// ------- GEMM2 routed: out += wl * (h_g @ Wd), atomic, 1D swizzled -------
__global__ __launch_bounds__(256) void gemm2_rt_kernel(
    const unsigned short* __restrict__ h_g,
    const unsigned short* __restrict__ wTd,
    float* __restrict__ out,
    const int* __restrict__ list, const float* __restrict__ wl,
    const int* __restrict__ cnt, int cap) {
  const int orig = blockIdx.x;
  const int wg = (orig & 7) * (gridDim.x >> 3) + (orig >> 3);
  const int e = wg >> 7;                 // 0..7
  const int rem = wg & 127;
  const int m0 = (rem >> 3) * 128, n0 = (rem & 7) * 128;
  const int count = min(cnt[e], cap);
  if (m0 >= count) return;
  const unsigned short* A = h_g + (size_t)e * cap * IP;
  const unsigned short* B = wTd + (size_t)(e + 1) * D_DIM * IP;

  __shared__ __align__(16) unsigned short a_lds[2][128 * 32];
  __shared__ __align__(16) unsigned short b_lds[2][128 * 32];
  const int tid = threadIdx.x;
  const int wave = tid >> 6, lane = tid & 63;
  const int mw = (wave >> 1) * 64, nw = (wave & 1) * 64;
  const int fr = lane & 15, fq = lane >> 4;
  const int ko = (tid & 3) * 8;
  const int ldr = tid >> 2;

  f32x4 acc[4][4];
  #pragma unroll
  for (int m = 0; m < 4; ++m)
    #pragma unroll
    for (int n = 0; n < 4; ++n) acc[m][n] = (f32x4)0.f;

  auto stage = [&](int buf, int k0) {
    #pragma unroll
    for (int r = 0; r < 2; ++r) {
      int lr = ldr + 64 * r;
      gload16(A + (size_t)(m0 + lr) * IP + k0 + ko, &a_lds[buf][lr * 32 + ko]);
      gload16(B + (size_t)(n0 + lr) * IP + k0 + ko, &b_lds[buf][lr * 32 + ko]);
    }
  };
  stage(0, 0);
  __syncthreads();
  int cur = 0;
  for (int t = 0; t < IP / 32; ++t) {
    if (t + 1 < IP / 32) stage(cur ^ 1, (t + 1) * 32);
    bf16x8 av[4], bv[4];
    #pragma unroll
    for (int m = 0; m < 4; ++m)
      av[m] = *reinterpret_cast<const bf16x8*>(&a_lds[cur][(mw + m * 16 + fr) * 32 + fq * 8]);
    #pragma unroll
    for (int n = 0; n < 4; ++n)
      bv[n] = *reinterpret_cast<const bf16x8*>(&b_lds[cur][(nw + n * 16 + fr) * 32 + fq * 8]);
    #pragma unroll
    for (int m = 0; m < 4; ++m)
      #pragma unroll
      for (int n = 0; n < 4; ++n)
        acc[m][n] = __builtin_amdgcn_mfma_f32_16x16x32_bf16(av[m], bv[n], acc[m][n], 0, 0, 0);
    __syncthreads();
    cur ^= 1;
  }
  #pragma unroll
  for (int m = 0; m < 4; ++m)
    #pragma unroll
    for (int q = 0; q < 4; ++q) {
      int slot = m0 + mw + m * 16 + fq * 4 + q;
      if (slot < count) {
        int t = list[e * cap + slot];
        float wgt = wl[e * cap + slot];
        #pragma unroll
        for (int n = 0; n < 4; ++n)
          atomicAdd(&out[(size_t)t * D_DIM + n0 + nw + n * 16 + fr], wgt * acc[m][n][q]);
      }
    }
}

extern "C" void kernel_launch(void* const* d_in, const int* in_sizes, int n_in,
                              void* d_out, int out_size, void* d_ws, size_t ws_size,
                              hipStream_t stream) {
  const float* x   = (const float*)d_in[0];
  const float* gw  = (const float*)d_in[1];
  const float* sgu = (const float*)d_in[2];
  const float* sdn = (const float*)d_in[3];
  const float* egu = (const float*)d_in[4];
  const float* edn = (const float*)d_in[5];
  float* out = (float*)d_out;

  char* p = (char*)d_ws;
  unsigned short* xb   = (unsigned short*)p; p += (size_t)T_TOK * D_DIM * 2;
  unsigned short* wTgu = (unsigned short*)p; p += (size_t)9 * NP2 * D_DIM * 2;
  unsigned short* wTd  = (unsigned short*)p; p += (size_t)9 * D_DIM * IP * 2;
  unsigned short* h_sh = (unsigned short*)p; p += (size_t)T_TOK * IP * 2;

  size_t fixed_tail = (size_t)T_TOK * 2 * (4 + 4) + 64 + 256;
  size_t used = (size_t)(p - (char*)d_ws) + fixed_tail;
  size_t per_cap = (size_t)E_EXP * (IP * 2 + 4 + 4);
  long avail = (long)ws_size - (long)used;
  int cap = (int)(avail > 0 ? avail / (long)per_cap : 0);
  cap &= ~127;
  if (cap > 2048) cap = 2048;
  if (cap < 1280) cap = 1280;

  unsigned short* h_g = (unsigned short*)p; p += (size_t)E_EXP * cap * IP * 2;
  int*   ti   = (int*)p;   p += (size_t)T_TOK * 2 * 4;
  float* tw   = (float*)p; p += (size_t)T_TOK * 2 * 4;
  int*   list = (int*)p;   p += (size_t)E_EXP * cap * 4;
  float* wl   = (float*)p; p += (size_t)E_EXP * cap * 4;
  int*   cnt  = (int*)p;

  cvt_x_kernel<<<(T_TOK * D_DIM) / (4 * 256), 256, 0, stream>>>(x, xb);
  router_kernel<<<T_TOK / 4, 256, 0, stream>>>(x, gw, ti, tw);
  zero_cnt_kernel<<<1, 64, 0, stream>>>(cnt);
  assign_kernel<<<T_TOK / 256, 256, 0, stream>>>(ti, tw, cnt, list, wl, cap);
  transpose_gu_kernel<<<dim3(D_DIM / 64, NP2 / 32, 9), 256, 0, stream>>>(sgu, egu, wTgu);
  transpose_d_kernel<<<dim3(IP / 64, D_DIM / 32, 9), 256, 0, stream>>>(sdn, edn, wTd);

  // fused gemm1: shared (e=0, 32 mb) + 8 routed (16 active mb budget, 32 decoded)
  gemm1_kernel<<<9 * 32 * 8, 256, 0, stream>>>(xb, wTgu, h_sh, h_g, list, cnt, cap);
  // gemm2: shared store first (stream order), then routed atomics
  gemm2_sh_kernel<<<dim3(T_TOK / 128, D_DIM / 128), 256, 0, stream>>>(h_sh, wTd, out);
  gemm2_rt_kernel<<<8 * 16 * 8, 256, 0, stream>>>(h_g, wTd, out, list, wl, cnt, cap);
}